// Round 6
// baseline (290.940 us; speedup 1.0000x reference)
//
#include <hip/hip_runtime.h>
#include <hip/hip_bf16.h>
#include <cstdint>

// ---------------- problem constants ----------------
#define BSZ   4
#define TSEQ  2048
#define DMOD  768
#define DCONV 384
#define DGRIF 384
#define DFFN  2048
#define BT    (BSZ*TSEQ)          // 8192
#define NG1   1920                // 2*DCONV + 3*DGRIF (logical)
#define G1LD  2048                // padded G1 row stride
#define EPS_  1e-6f

typedef __bf16 bf16;
typedef __bf16 bf16x8 __attribute__((ext_vector_type(8)));
typedef float  f32x4  __attribute__((ext_vector_type(4)));

__device__ __forceinline__ float sigmoidf_(float x) { return 1.f / (1.f + __expf(-x)); }

// async global->LDS, 16B per lane; LDS dest is wave-uniform base (+lane*16 in HW)
__device__ __forceinline__ void gload_lds16(const void* g, void* l) {
  __builtin_amdgcn_global_load_lds(
      (const __attribute__((address_space(1))) void*)(uintptr_t)g,
      (__attribute__((address_space(3))) void*)(uint32_t)(uintptr_t)l,
      16, 0, 0);
}

// bijective XCD swizzle: nwg % 8 == 0 for all our grids
__device__ __forceinline__ int swz_wg() {
  const int nwg = gridDim.x;
  const int bid = blockIdx.x;
  const int cpx = nwg >> 3;
  return (bid & 7) * cpx + (bid >> 3);
}

#define SBAR() __builtin_amdgcn_s_barrier()
#define VMCNT6() asm volatile("s_waitcnt vmcnt(6)" ::: "memory")
#define VMCNT4() asm volatile("s_waitcnt vmcnt(4)" ::: "memory")
#define VMCNT0() asm volatile("s_waitcnt vmcnt(0)" ::: "memory")

// =====================================================================
// 8-phase 256x256 GEMM (T2+T3+T4+T5), BK=64, 8 waves (2M x 4N).
// LDS (dynamic 128 KB): A: [buf][kk][256 rows][32 cols] bf16 (buf stride 32 KB,
// kk stride 16 KB, row stride 64 B); B same at +64 KB.
// Swizzle: stored slot s holds global slot s ^ ((row>>1)&3)  (involution).
// Per K-tile phases: (mh0,kk0)+LDB(kk0) | (mh1,kk0) | (mh0,kk1)+LDB(kk1) | (mh1,kk1)
// Stages: ph1:B-k0(t+1)  ph2:A-k1(t+1)  ph3:B-k1(t+1)  ph4:A-k0(t+2)
// Waits: end-ph2 / end-ph4 vmcnt(6)  (tail: vmcnt(0)/vmcnt(4)) -- FIFO-derived.
// EPI 0: bf16 store (ldc stride).  EPI 1: fused SwiGLU with interleaved w1/w3.
// =====================================================================
template <int EPI>
__global__ __launch_bounds__(512, 2) void gemm256(
    const bf16* __restrict__ A, const bf16* __restrict__ Bt, bf16* __restrict__ C,
    int K, int nx, int ldc)
{
  extern __shared__ __align__(16) char lds_dyn[];

  const int wg = swz_wg();
  const int m0 = (wg / nx) * 256;
  const int bx = wg % nx;
  const int n0 = bx * 256;
  const int tid  = threadIdx.x;
  const int lane = tid & 63;
  const int wr = (tid >> 6) >> 2;   // 0..1
  const int wc = (tid >> 6) & 3;    // 0..3
  const int lr = lane & 15;
  const int lk4 = lane >> 4;        // 0..3

  f32x4 acc[8][4] = {};
  bf16x8 af[4], bfr[4];

  const int nt = K >> 6;            // K-tiles (>= 3)

  auto ldA = [&](int cur, int kk, int row) -> bf16x8 {
    const int off = (cur << 15) + (kk << 14) + row * 64 + ((lk4 ^ ((row >> 1) & 3)) << 4);
    return *reinterpret_cast<const bf16x8*>(&lds_dyn[off]);
  };
  auto ldB = [&](int cur, int kk, int row) -> bf16x8 {
    const int off = 65536 + (cur << 15) + (kk << 14) + row * 64 + ((lk4 ^ ((row >> 1) & 3)) << 4);
    return *reinterpret_cast<const bf16x8*>(&lds_dyn[off]);
  };
  auto stageA = [&](int t, int kk) {
    const bf16* g = A + (size_t)m0 * K + t * 64 + kk * 32;
    const int dstbase = ((t & 1) << 15) + (kk << 14);
    #pragma unroll
    for (int p = 0; p < 2; ++p) {
      const int f = (p << 9) + tid;
      const int row = f >> 2;
      const int gs = (f & 3) ^ ((row >> 1) & 3);
      gload_lds16(g + (size_t)row * K + gs * 8,
                  &lds_dyn[dstbase + (p << 13) + ((tid >> 6) << 10)]);
    }
  };
  auto stageB = [&](int t, int kk) {
    const bf16* g = Bt + (size_t)n0 * K + t * 64 + kk * 32;
    const int dstbase = 65536 + ((t & 1) << 15) + (kk << 14);
    #pragma unroll
    for (int p = 0; p < 2; ++p) {
      const int f = (p << 9) + tid;
      const int row = f >> 2;
      const int gs = (f & 3) ^ ((row >> 1) & 3);
      gload_lds16(g + (size_t)row * K + gs * 8,
                  &lds_dyn[dstbase + (p << 13) + ((tid >> 6) << 10)]);
    }
  };

  // prologue: A-k0(0), B-k0(0), A-k1(0), B-k1(0), A-k0(1); force oldest 2 halves
  stageA(0, 0); stageB(0, 0); stageA(0, 1); stageB(0, 1); stageA(1, 0);
  VMCNT6();
  SBAR();

  for (int t = 0; t < nt; ++t) {
    const int cur = t & 1;
    const bool s1 = (t + 1 < nt), s2 = (t + 2 < nt);

    // ---- phase 1: (mh0, kk0), load B(kk0); stage B-k0(t+1)
    #pragma unroll
    for (int i = 0; i < 4; ++i) af[i] = ldA(cur, 0, wr * 128 + i * 16 + lr);
    #pragma unroll
    for (int i = 0; i < 4; ++i) bfr[i] = ldB(cur, 0, wc * 64 + i * 16 + lr);
    if (s1) stageB(t + 1, 0);
    SBAR();
    __builtin_amdgcn_s_setprio(1);
    #pragma unroll
    for (int mi = 0; mi < 4; ++mi)
      #pragma unroll
      for (int ni = 0; ni < 4; ++ni)
        acc[mi][ni] = __builtin_amdgcn_mfma_f32_16x16x32_bf16(af[mi], bfr[ni], acc[mi][ni], 0, 0, 0);
    __builtin_amdgcn_s_setprio(0);
    SBAR();

    // ---- phase 2: (mh1, kk0); stage A-k1(t+1); wait for next phase's halves
    #pragma unroll
    for (int i = 0; i < 4; ++i) af[i] = ldA(cur, 0, wr * 128 + 64 + i * 16 + lr);
    if (s1) stageA(t + 1, 1);
    SBAR();
    __builtin_amdgcn_s_setprio(1);
    #pragma unroll
    for (int mi = 0; mi < 4; ++mi)
      #pragma unroll
      for (int ni = 0; ni < 4; ++ni)
        acc[4 + mi][ni] = __builtin_amdgcn_mfma_f32_16x16x32_bf16(af[mi], bfr[ni], acc[4 + mi][ni], 0, 0, 0);
    __builtin_amdgcn_s_setprio(0);
    if (s1) { VMCNT6(); } else { VMCNT0(); }   // forces A-k1(t), B-k1(t)
    SBAR();

    // ---- phase 3: (mh0, kk1), load B(kk1); stage B-k1(t+1)
    #pragma unroll
    for (int i = 0; i < 4; ++i) af[i] = ldA(cur, 1, wr * 128 + i * 16 + lr);
    #pragma unroll
    for (int i = 0; i < 4; ++i) bfr[i] = ldB(cur, 1, wc * 64 + i * 16 + lr);
    if (s1) stageB(t + 1, 1);
    SBAR();
    __builtin_amdgcn_s_setprio(1);
    #pragma unroll
    for (int mi = 0; mi < 4; ++mi)
      #pragma unroll
      for (int ni = 0; ni < 4; ++ni)
        acc[mi][ni] = __builtin_amdgcn_mfma_f32_16x16x32_bf16(af[mi], bfr[ni], acc[mi][ni], 0, 0, 0);
    __builtin_amdgcn_s_setprio(0);
    SBAR();

    // ---- phase 4: (mh1, kk1); stage A-k0(t+2); wait for next tile's k0 halves
    #pragma unroll
    for (int i = 0; i < 4; ++i) af[i] = ldA(cur, 1, wr * 128 + 64 + i * 16 + lr);
    if (s2) stageA(t + 2, 0);
    SBAR();
    __builtin_amdgcn_s_setprio(1);
    #pragma unroll
    for (int mi = 0; mi < 4; ++mi)
      #pragma unroll
      for (int ni = 0; ni < 4; ++ni)
        acc[4 + mi][ni] = __builtin_amdgcn_mfma_f32_16x16x32_bf16(af[mi], bfr[ni], acc[4 + mi][ni], 0, 0, 0);
    __builtin_amdgcn_s_setprio(0);
    if (s2) { VMCNT6(); } else if (s1) { VMCNT4(); }  // forces A-k0(t+1), B-k0(t+1)
    SBAR();
  }

  // ---------------- epilogue ----------------
  if (EPI == 0) {
    #pragma unroll
    for (int a = 0; a < 8; ++a)
      #pragma unroll
      for (int ni = 0; ni < 4; ++ni)
        #pragma unroll
        for (int reg = 0; reg < 4; ++reg) {
          const int r = m0 + wr * 128 + a * 16 + lk4 * 4 + reg;
          const int c = n0 + wc * 64 + ni * 16 + lr;
          C[(size_t)r * ldc + c] = (bf16)acc[a][ni][reg];
        }
  } else {
    // interleaved w1/w3: wc even holds p1 of H-group (2bx + wc/2); wc odd holds p3.
    char* comb = lds_dyn;            // 64 KB dead A-region; [q][256 rows][64 cols] bf16
    const int q = wc >> 1;
    if (wc & 1) {
      #pragma unroll
      for (int a = 0; a < 8; ++a)
        #pragma unroll
        for (int ni = 0; ni < 4; ++ni)
          #pragma unroll
          for (int reg = 0; reg < 4; ++reg) {
            const int r = wr * 128 + a * 16 + lk4 * 4 + reg;
            const int col = ni * 16 + lr;
            *reinterpret_cast<bf16*>(&comb[(q << 15) + r * 128 + col * 2]) = (bf16)acc[a][ni][reg];
          }
    }
    SBAR();
    if (!(wc & 1)) {
      #pragma unroll
      for (int a = 0; a < 8; ++a)
        #pragma unroll
        for (int ni = 0; ni < 4; ++ni)
          #pragma unroll
          for (int reg = 0; reg < 4; ++reg) {
            const int r = wr * 128 + a * 16 + lk4 * 4 + reg;
            const int col = ni * 16 + lr;
            const float p3 = (float)*reinterpret_cast<const bf16*>(&comb[(q << 15) + r * 128 + col * 2]);
            const float p1 = acc[a][ni][reg];
            C[(size_t)(m0 + r) * ldc + (bx * 2 + q) * 64 + col] = (bf16)(p1 * sigmoidf_(p1) * p3);
          }
    }
  }
}

// ---------------- weight transpose + bf16 cast ----------------
// MODE 0: out_row = c (zero-fill rows c in [C, Cpad)).
// MODE 1: out_row = (c/64)*128 + half + (c%64)   (w1/w3 interleave)
template <int MODE>
__global__ __launch_bounds__(256) void transpose_bf16_kernel(
    const float* __restrict__ W, bf16* __restrict__ Wt, int R, int C, int Cpad, int half)
{
  __shared__ float tile[32][33];
  const int tc = blockIdx.x * 32;
  const int tr = blockIdx.y * 32;
  const int lx = threadIdx.x;
  const int ly = threadIdx.y;
  #pragma unroll
  for (int i = ly; i < 32; i += 8) {
    int r = tr + i, c = tc + lx;
    tile[i][lx] = (r < R && c < C) ? W[(size_t)r * C + c] : 0.f;
  }
  __syncthreads();
  #pragma unroll
  for (int i = ly; i < 32; i += 8) {
    int oc = tc + i;
    int orr = tr + lx;
    if (orr < R) {
      if (MODE == 0) {
        if (oc < Cpad) Wt[(size_t)oc * R + orr] = (bf16)tile[lx][i];
      } else {
        if (oc < C) {
          int orow = ((oc >> 6) << 7) + half + (oc & 63);
          Wt[(size_t)orow * R + orr] = (bf16)tile[lx][i];
        }
      }
    }
  }
}

// ---------------- rmsnorm (x fp32 -> out bf16) ----------------
__global__ __launch_bounds__(256) void rmsnorm_kernel(
    const float* __restrict__ x, const float* __restrict__ w, bf16* __restrict__ out)
{
  __shared__ float sbuf[4];
  const int row = blockIdx.x;
  const int tid = threadIdx.x;
  const float* xr = x + (size_t)row * DMOD;
  float v0 = xr[tid], v1 = xr[tid + 256], v2 = xr[tid + 512];
  float s = v0*v0 + v1*v1 + v2*v2;
  #pragma unroll
  for (int o = 32; o > 0; o >>= 1) s += __shfl_down(s, o, 64);
  if ((tid & 63) == 0) sbuf[tid >> 6] = s;
  __syncthreads();
  float tot = sbuf[0] + sbuf[1] + sbuf[2] + sbuf[3];
  float rms = rsqrtf(tot * (1.f / (float)DMOD) + EPS_);
  bf16* orow = out + (size_t)row * DMOD;
  orow[tid]       = (bf16)(v0 * rms * w[tid]);
  orow[tid + 256] = (bf16)(v1 * rms * w[tid + 256]);
  orow[tid + 512] = (bf16)(v2 * rms * w[tid + 512]);
}

// ---------------- narrow GEMM: 128x64 tile (N=768 GEMMs) ----------------
// EPI 0: momentum epilogue.  EPI 1: C += acc.
template <int EPI>
__global__ __launch_bounds__(256) void gemm_n64(
    const bf16* __restrict__ A, const bf16* __restrict__ Bt, float* __restrict__ C,
    const float* __restrict__ xin, const float* __restrict__ vin,
    float* __restrict__ outv, const float* __restrict__ log_beta,
    int M, int N, int K, int nx)
{
  __shared__ alignas(16) unsigned short As[128 * 64];
  __shared__ alignas(16) unsigned short Bs[64 * 64];

  const int wg = swz_wg();
  const int m0 = (wg / nx) * 128, n0 = (wg % nx) * 64;
  const int tid  = threadIdx.x;
  const int wave = tid >> 6;
  const int lane = tid & 63;
  const int wr = wave >> 1, wc = wave & 1;

  f32x4 acc[4][2] = {};
  const int srow = lane >> 3;
  const int scol = ((lane & 7) ^ srow) * 8;
  const int lr = lane & 15;
  const int lsw = lr & 7;
  const int lk4 = lane >> 4;

  for (int k0 = 0; k0 < K; k0 += 64) {
    __syncthreads();
    #pragma unroll
    for (int it = 0; it < 6; ++it) {
      const int chunk = wave * 6 + it;
      if (chunk < 16) {
        const int row = chunk * 8 + srow;
        gload_lds16(A + (size_t)(m0 + row) * K + k0 + scol, (char*)As + chunk * 1024);
      } else {
        const int row = (chunk - 16) * 8 + srow;
        gload_lds16(Bt + (size_t)(n0 + row) * K + k0 + scol, (char*)Bs + (chunk - 16) * 1024);
      }
    }
    __syncthreads();
    #pragma unroll
    for (int kk = 0; kk < 2; ++kk) {
      bf16x8 af[4], bfr[2];
      #pragma unroll
      for (int i = 0; i < 4; ++i)
        af[i] = *reinterpret_cast<const bf16x8*>(
            &As[(wr*64 + i*16 + lr) * 64 + (((kk*4 + lk4) ^ lsw) * 8)]);
      #pragma unroll
      for (int i = 0; i < 2; ++i)
        bfr[i] = *reinterpret_cast<const bf16x8*>(
            &Bs[(wc*32 + i*16 + lr) * 64 + (((kk*4 + lk4) ^ lsw) * 8)]);
      #pragma unroll
      for (int mi = 0; mi < 4; ++mi)
        #pragma unroll
        for (int ni = 0; ni < 2; ++ni)
          acc[mi][ni] = __builtin_amdgcn_mfma_f32_16x16x32_bf16(af[mi], bfr[ni], acc[mi][ni], 0, 0, 0);
    }
  }

  const float beta = (EPI == 0) ? sigmoidf_(log_beta[0]) : 0.f;
  #pragma unroll
  for (int mi = 0; mi < 4; ++mi)
    #pragma unroll
    for (int ni = 0; ni < 2; ++ni)
      #pragma unroll
      for (int reg = 0; reg < 4; ++reg) {
        const int r = m0 + wr*64 + mi*16 + (lane >> 4) * 4 + reg;
        const int c = n0 + wc*32 + ni*16 + (lane & 15);
        const size_t off = (size_t)r * N + c;
        float v = acc[mi][ni][reg];
        if (EPI == 0) {
          float vel = beta * vin[off] + v;
          float x1  = xin[off] + vel;
          outv[off] = vel;
          C[off] = x1;
        } else {
          C[off] += v;
        }
      }
}

// ---------------- RG-LRU 2-pass chunked scan + fused conv (bf16 G1, stride G1LD) ----------------
#define NCH  32
#define CLEN 64

__device__ __forceinline__ void lru_step(const bf16* row, int c, float coef,
                                         float& a, float& g)
{
  float v  = (float)row[2*DCONV + c];
  float r  = sigmoidf_((float)row[2*DCONV + DGRIF + c]);
  float is = sigmoidf_((float)row[2*DCONV + 2*DGRIF + c]);
  float la = coef * r;
  a = __expf(la);
  g = sqrtf(fmaxf(1.f - __expf(2.f * la), EPS_)) * (is * v);
}

__global__ __launch_bounds__(256) void lru_pass1(
    const bf16* __restrict__ g1, const float* __restrict__ lam,
    float* __restrict__ cA, float* __restrict__ cB)
{
  const int idx = blockIdx.x * 256 + threadIdx.x;
  const int c = idx % DGRIF;
  const int rest = idx / DGRIF;
  const int j = rest & (NCH - 1);
  const int b = rest / NCH;
  const float coef = -8.f * log1pf(__expf(lam[c]));
  const bf16* base = g1 + (size_t)(b * TSEQ + j * CLEN) * G1LD;
  float A = 1.f, Bv = 0.f;
  #pragma unroll 4
  for (int t = 0; t < CLEN; ++t) {
    float a, g;
    lru_step(base + (size_t)t * G1LD, c, coef, a, g);
    A *= a;
    Bv = a * Bv + g;
  }
  cA[((size_t)b * DGRIF + c) * NCH + j] = A;
  cB[((size_t)b * DGRIF + c) * NCH + j] = Bv;
}

__global__ __launch_bounds__(256) void lru_pass2(
    const bf16* __restrict__ g1, const float* __restrict__ lam,
    const float* __restrict__ cA, const float* __restrict__ cB,
    const float* __restrict__ dw, bf16* __restrict__ mixin)
{
  const int idx = blockIdx.x * 256 + threadIdx.x;
  const int c = idx % DGRIF;
  const int rest = idx / DGRIF;
  const int j = rest & (NCH - 1);
  const int b = rest / NCH;
  const float coef = -8.f * log1pf(__expf(lam[c]));
  float Hc = 0.f;
  const float* pa = cA + ((size_t)b * DGRIF + c) * NCH;
  const float* pb = cB + ((size_t)b * DGRIF + c) * NCH;
  for (int k = 0; k < j; ++k) Hc = pa[k] * Hc + pb[k];

  const int t0 = j * CLEN;
  const bf16* base = g1 + (size_t)(b * TSEQ + t0) * G1LD;
  const float w0 = dw[c*3], w1 = dw[c*3 + 1], w2 = dw[c*3 + 2];
  float u1 = (t0 >= 1) ? (float)base[-(ptrdiff_t)G1LD + c]     : 0.f;
  float u0 = (t0 >= 2) ? (float)base[-(ptrdiff_t)(2*G1LD) + c] : 0.f;

  bf16* mbase = mixin + (size_t)(b * TSEQ + t0) * DMOD;
  #pragma unroll 4
  for (int t = 0; t < CLEN; ++t) {
    const bf16* row = base + (size_t)t * G1LD;
    float u2 = (float)row[c];
    float gg = (float)row[DCONV + c];
    float conv = u0 * w0 + u1 * w1 + u2 * w2;
    mbase[(size_t)t * DMOD + c] = (bf16)(conv * (gg * sigmoidf_(gg)));
    u0 = u1; u1 = u2;
    float a, g;
    lru_step(row, c, coef, a, g);
    Hc = a * Hc + g;
    mbase[(size_t)t * DMOD + DCONV + c] = (bf16)Hc;
  }
}

// ---------------- launcher ----------------
extern "C" void kernel_launch(void* const* d_in, const int* in_sizes, int n_in,
                              void* d_out, int out_size, void* d_ws, size_t ws_size,
                              hipStream_t stream)
{
  const float* x         = (const float*)d_in[0];
  const float* vel_in    = (const float*)d_in[1];
  const float* pre_w     = (const float*)d_in[2];
  const float* conv_in_w = (const float*)d_in[3];
  const float* conv_dw   = (const float*)d_in[4];
  const float* gv        = (const float*)d_in[5];
  const float* gr        = (const float*)d_in[6];
  const float* gi        = (const float*)d_in[7];
  const float* lam       = (const float*)d_in[8];
  const float* out_w     = (const float*)d_in[9];
  const float* log_beta  = (const float*)d_in[10];
  const float* ffn_w     = (const float*)d_in[11];
  const float* w1        = (const float*)d_in[12];
  const float* w3        = (const float*)d_in[13];
  const float* w2        = (const float*)d_in[14];

  char* ws = (char*)d_ws;
  size_t off = 0;
  auto alloc = [&](size_t bytes) { void* p = ws + off; off += (bytes + 255) & ~(size_t)255; return p; };

  bf16*  WT_G1  = (bf16*)alloc((size_t)G1LD * DMOD * 2);         // [2048][768] padded
  bf16*  WT_OUT = (bf16*)alloc((size_t)DMOD * DMOD * 2);
  bf16*  WT_W13 = (bf16*)alloc((size_t)2 * DFFN * DMOD * 2);     // [4096][768] interleaved
  bf16*  WT_W2  = (bf16*)alloc((size_t)DMOD * DFFN * 2);
  float* CA     = (float*)alloc((size_t)BSZ * DGRIF * NCH * 4);
  float* CB     = (float*)alloc((size_t)BSZ * DGRIF * NCH * 4);
  bf16*  XN     = (bf16*)alloc((size_t)BT * DMOD * 2);
  bf16*  G1     = (bf16*)alloc((size_t)BT * G1LD * 2);           // 33.6 MB (padded)
  bf16*  MIXIN  = (bf16*)alloc((size_t)BT * DMOD * 2);
  bf16*  H      = (bf16*)alloc((size_t)BT * DFFN * 2);
  bf16*  NORMED = (bf16*)alloc((size_t)BT * DMOD * 2);

  float* OUTX   = (float*)d_out;
  float* OUTV   = OUTX + (size_t)BT * DMOD;

  hipFuncSetAttribute((const void*)gemm256<0>, hipFuncAttributeMaxDynamicSharedMemorySize, 131072);
  hipFuncSetAttribute((const void*)gemm256<1>, hipFuncAttributeMaxDynamicSharedMemorySize, 131072);

  const dim3 tb(32, 8);
  // weight transposes -> bf16 [N][K]; WT_G1 rows 1920..2047 zero-padded
  hipMemsetAsync(WT_G1 + (size_t)NG1 * DMOD, 0, (size_t)(G1LD - NG1) * DMOD * 2, stream);
  transpose_bf16_kernel<0><<<dim3(DMOD/32,  DMOD/32), tb, 0, stream>>>(conv_in_w, WT_G1, DMOD, DMOD, DMOD, 0);
  transpose_bf16_kernel<0><<<dim3(DGRIF/32, DMOD/32), tb, 0, stream>>>(gv, WT_G1 + (size_t)(2*DCONV) * DMOD, DMOD, DGRIF, DGRIF, 0);
  transpose_bf16_kernel<0><<<dim3(DGRIF/32, DMOD/32), tb, 0, stream>>>(gr, WT_G1 + (size_t)(2*DCONV + DGRIF) * DMOD, DMOD, DGRIF, DGRIF, 0);
  transpose_bf16_kernel<0><<<dim3(DGRIF/32, DMOD/32), tb, 0, stream>>>(gi, WT_G1 + (size_t)(2*DCONV + 2*DGRIF) * DMOD, DMOD, DGRIF, DGRIF, 0);
  transpose_bf16_kernel<0><<<dim3(DMOD/32,  DMOD/32), tb, 0, stream>>>(out_w, WT_OUT, DMOD, DMOD, DMOD, 0);
  transpose_bf16_kernel<1><<<dim3(DFFN/32,  DMOD/32), tb, 0, stream>>>(w1, WT_W13, DMOD, DFFN, DFFN, 0);
  transpose_bf16_kernel<1><<<dim3(DFFN/32,  DMOD/32), tb, 0, stream>>>(w3, WT_W13, DMOD, DFFN, DFFN, 64);
  transpose_bf16_kernel<0><<<dim3(DMOD/32,  DFFN/32), tb, 0, stream>>>(w2, WT_W2, DFFN, DMOD, DMOD, 0);

  // pre-norm
  rmsnorm_kernel<<<BT, 256, 0, stream>>>(x, pre_w, XN);

  // GEMM1 (8-phase 256^2): [8192,768] @ [768,2048pad] -> G1 (bf16, stride 2048)
  gemm256<0><<<(BT/256) * (G1LD/256), 512, 131072, stream>>>(XN, WT_G1, G1, DMOD, G1LD/256, G1LD);

  // RG-LRU branch + fused conv branch -> MIXIN
  lru_pass1<<<(BSZ * NCH * DGRIF) / 256, 256, 0, stream>>>(G1, lam, CA, CB);
  lru_pass2<<<(BSZ * NCH * DGRIF) / 256, 256, 0, stream>>>(G1, lam, CA, CB, conv_dw, MIXIN);

  // GEMM2 + momentum epilogue: OUTX = x + vel, OUTV = vel
  gemm_n64<0><<<(DMOD/64) * (BT/128), 256, 0, stream>>>(MIXIN, WT_OUT, OUTX, x, vel_in, OUTV,
                                                        log_beta, BT, DMOD, DMOD, DMOD/64);

  // ffn rmsnorm on x1
  rmsnorm_kernel<<<BT, 256, 0, stream>>>(OUTX, ffn_w, NORMED);

  // fused FFN up-proj + SwiGLU (8-phase 256^2) -> H (bf16)
  gemm256<1><<<(BT/256) * (2*DFFN/256), 512, 131072, stream>>>(NORMED, WT_W13, H, DMOD, 2*DFFN/256, DFFN);

  // down-proj, accumulate into OUTX
  gemm_n64<1><<<(DMOD/64) * (BT/128), 256, 0, stream>>>(H, WT_W2, OUTX, nullptr, nullptr, nullptr,
                                                        nullptr, BT, DMOD, DFFN, DMOD/64);
}

// Round 7
// 288.287 us; speedup vs baseline: 1.0092x; 1.0092x over previous
//
#include <hip/hip_runtime.h>
#include <hip/hip_bf16.h>
#include <cstdint>

// ---------------- problem constants ----------------
#define BSZ   4
#define TSEQ  2048
#define DMOD  768
#define DCONV 384
#define DGRIF 384
#define DFFN  2048
#define BT    (BSZ*TSEQ)          // 8192
#define NG1   1920                // 2*DCONV + 3*DGRIF (logical)
#define G1LD  2048                // padded G1 row stride
#define EPS_  1e-6f

typedef __bf16 bf16;
typedef __bf16 bf16x8 __attribute__((ext_vector_type(8)));
typedef float  f32x4  __attribute__((ext_vector_type(4)));

__device__ __forceinline__ float sigmoidf_(float x) { return 1.f / (1.f + __expf(-x)); }

__device__ __forceinline__ void gload_lds16(const void* g, void* l) {
  __builtin_amdgcn_global_load_lds(
      (const __attribute__((address_space(1))) void*)(uintptr_t)g,
      (__attribute__((address_space(3))) void*)(uint32_t)(uintptr_t)l,
      16, 0, 0);
}

__device__ __forceinline__ int swz_wg() {
  const int nwg = gridDim.x;
  const int bid = blockIdx.x;
  const int cpx = nwg >> 3;
  return (bid & 7) * cpx + (bid >> 3);
}

#define SBAR() __builtin_amdgcn_s_barrier()
#define VM8() asm volatile("s_waitcnt vmcnt(8)" ::: "memory")
#define VM4() asm volatile("s_waitcnt vmcnt(4)" ::: "memory")
#define VM0() asm volatile("s_waitcnt vmcnt(0)" ::: "memory")

// =====================================================================
// 8-phase 256x256 GEMM, BK=64, 8 waves (2M x 4N), deep-lookahead v2:
// tile t stages {A-k1(t+1), B-k1(t+1), A-k0(t+2), B-k0(t+2)} (one half/phase);
// waits vmcnt(8) at end-ph2 (forces k1(t)) and end-ph4 (forces k0(t+1)) --
// each forced half was issued 5-6 phases (>=1500 cyc) earlier. Tails VM0/VM4.
// LDS 128 KB: A [buf][kk][256][32] bf16; B same at +64 KB.
// Slot swizzle: stored slot s = global slot s ^ ((row>>1)&3).
// EPI 0: bf16 store.  EPI 1: fused SwiGLU (interleaved w1/w3 pairs).
// =====================================================================
template <int EPI>
__global__ __launch_bounds__(512, 2) void gemm256(
    const bf16* __restrict__ A, const bf16* __restrict__ Bt, bf16* __restrict__ C,
    int K, int nx, int ldc)
{
  extern __shared__ __align__(16) char lds_dyn[];

  const int wg = swz_wg();
  const int m0 = (wg / nx) * 256;
  const int bx = wg % nx;
  const int n0 = bx * 256;
  const int tid  = threadIdx.x;
  const int lane = tid & 63;
  const int wr = (tid >> 6) >> 2;   // 0..1
  const int wc = (tid >> 6) & 3;    // 0..3
  const int lr = lane & 15;
  const int lk4 = lane >> 4;        // 0..3

  f32x4 acc[8][4] = {};
  bf16x8 af[4], bfr[4];

  const int nt = K >> 6;            // K-tiles (>= 3)

  auto ldA = [&](int cur, int kk, int row) -> bf16x8 {
    const int off = (cur << 15) + (kk << 14) + row * 64 + ((lk4 ^ ((row >> 1) & 3)) << 4);
    return *reinterpret_cast<const bf16x8*>(&lds_dyn[off]);
  };
  auto ldB = [&](int cur, int kk, int row) -> bf16x8 {
    const int off = 65536 + (cur << 15) + (kk << 14) + row * 64 + ((lk4 ^ ((row >> 1) & 3)) << 4);
    return *reinterpret_cast<const bf16x8*>(&lds_dyn[off]);
  };
  auto stageA = [&](int t, int kk) {
    const bf16* g = A + (size_t)m0 * K + t * 64 + kk * 32;
    const int dstbase = ((t & 1) << 15) + (kk << 14);
    #pragma unroll
    for (int p = 0; p < 2; ++p) {
      const int f = (p << 9) + tid;
      const int row = f >> 2;
      const int gs = (f & 3) ^ ((row >> 1) & 3);
      gload_lds16(g + (size_t)row * K + gs * 8,
                  &lds_dyn[dstbase + (p << 13) + ((tid >> 6) << 10)]);
    }
  };
  auto stageB = [&](int t, int kk) {
    const bf16* g = Bt + (size_t)n0 * K + t * 64 + kk * 32;
    const int dstbase = 65536 + ((t & 1) << 15) + (kk << 14);
    #pragma unroll
    for (int p = 0; p < 2; ++p) {
      const int f = (p << 9) + tid;
      const int row = f >> 2;
      const int gs = (f & 3) ^ ((row >> 1) & 3);
      gload_lds16(g + (size_t)row * K + gs * 8,
                  &lds_dyn[dstbase + (p << 13) + ((tid >> 6) << 10)]);
    }
  };

  // prologue: k0(0), k1(0), k0(1) in issue order; force k0(0)
  stageA(0, 0); stageB(0, 0); stageA(0, 1); stageB(0, 1); stageA(1, 0); stageB(1, 0);
  VM8();
  SBAR();

  for (int t = 0; t < nt; ++t) {
    const int cur = t & 1;
    const bool s1 = (t + 1 < nt), s2 = (t + 2 < nt);

    // ---- phase 1: (mh0, kk0); stage A-k1(t+1)
    #pragma unroll
    for (int i = 0; i < 4; ++i) af[i] = ldA(cur, 0, wr * 128 + i * 16 + lr);
    #pragma unroll
    for (int i = 0; i < 4; ++i) bfr[i] = ldB(cur, 0, wc * 64 + i * 16 + lr);
    if (s1) stageA(t + 1, 1);
    SBAR();
    __builtin_amdgcn_s_setprio(1);
    #pragma unroll
    for (int mi = 0; mi < 4; ++mi)
      #pragma unroll
      for (int ni = 0; ni < 4; ++ni)
        acc[mi][ni] = __builtin_amdgcn_mfma_f32_16x16x32_bf16(af[mi], bfr[ni], acc[mi][ni], 0, 0, 0);
    __builtin_amdgcn_s_setprio(0);
    SBAR();

    // ---- phase 2: (mh1, kk0); stage B-k1(t+1); wait forces k1(t)
    #pragma unroll
    for (int i = 0; i < 4; ++i) af[i] = ldA(cur, 0, wr * 128 + 64 + i * 16 + lr);
    if (s1) stageB(t + 1, 1);
    SBAR();
    __builtin_amdgcn_s_setprio(1);
    #pragma unroll
    for (int mi = 0; mi < 4; ++mi)
      #pragma unroll
      for (int ni = 0; ni < 4; ++ni)
        acc[4 + mi][ni] = __builtin_amdgcn_mfma_f32_16x16x32_bf16(af[mi], bfr[ni], acc[4 + mi][ni], 0, 0, 0);
    __builtin_amdgcn_s_setprio(0);
    if (s1) { VM8(); } else { VM0(); }
    SBAR();

    // ---- phase 3: (mh0, kk1); stage A-k0(t+2)
    #pragma unroll
    for (int i = 0; i < 4; ++i) af[i] = ldA(cur, 1, wr * 128 + i * 16 + lr);
    #pragma unroll
    for (int i = 0; i < 4; ++i) bfr[i] = ldB(cur, 1, wc * 64 + i * 16 + lr);
    if (s2) stageA(t + 2, 0);
    SBAR();
    __builtin_amdgcn_s_setprio(1);
    #pragma unroll
    for (int mi = 0; mi < 4; ++mi)
      #pragma unroll
      for (int ni = 0; ni < 4; ++ni)
        acc[mi][ni] = __builtin_amdgcn_mfma_f32_16x16x32_bf16(af[mi], bfr[ni], acc[mi][ni], 0, 0, 0);
    __builtin_amdgcn_s_setprio(0);
    SBAR();

    // ---- phase 4: (mh1, kk1); stage B-k0(t+2); wait forces k0(t+1)
    #pragma unroll
    for (int i = 0; i < 4; ++i) af[i] = ldA(cur, 1, wr * 128 + 64 + i * 16 + lr);
    if (s2) stageB(t + 2, 0);
    SBAR();
    __builtin_amdgcn_s_setprio(1);
    #pragma unroll
    for (int mi = 0; mi < 4; ++mi)
      #pragma unroll
      for (int ni = 0; ni < 4; ++ni)
        acc[4 + mi][ni] = __builtin_amdgcn_mfma_f32_16x16x32_bf16(af[mi], bfr[ni], acc[4 + mi][ni], 0, 0, 0);
    __builtin_amdgcn_s_setprio(0);
    if (s2) { VM8(); } else if (s1) { VM4(); }
    SBAR();
  }

  // ---------------- epilogue ----------------
  if (EPI == 0) {
    #pragma unroll
    for (int a = 0; a < 8; ++a)
      #pragma unroll
      for (int ni = 0; ni < 4; ++ni)
        #pragma unroll
        for (int reg = 0; reg < 4; ++reg) {
          const int r = m0 + wr * 128 + a * 16 + lk4 * 4 + reg;
          const int c = n0 + wc * 64 + ni * 16 + lr;
          C[(size_t)r * ldc + c] = (bf16)acc[a][ni][reg];
        }
  } else {
    char* comb = lds_dyn;            // dead A-region; [q][256 rows][64 cols] bf16
    const int q = wc >> 1;
    if (wc & 1) {
      #pragma unroll
      for (int a = 0; a < 8; ++a)
        #pragma unroll
        for (int ni = 0; ni < 4; ++ni)
          #pragma unroll
          for (int reg = 0; reg < 4; ++reg) {
            const int r = wr * 128 + a * 16 + lk4 * 4 + reg;
            const int col = ni * 16 + lr;
            *reinterpret_cast<bf16*>(&comb[(q << 15) + r * 128 + col * 2]) = (bf16)acc[a][ni][reg];
          }
    }
    SBAR();
    if (!(wc & 1)) {
      #pragma unroll
      for (int a = 0; a < 8; ++a)
        #pragma unroll
        for (int ni = 0; ni < 4; ++ni)
          #pragma unroll
          for (int reg = 0; reg < 4; ++reg) {
            const int r = wr * 128 + a * 16 + lk4 * 4 + reg;
            const int col = ni * 16 + lr;
            const float p3 = (float)*reinterpret_cast<const bf16*>(&comb[(q << 15) + r * 128 + col * 2]);
            const float p1 = acc[a][ni][reg];
            C[(size_t)(m0 + r) * ldc + (bx * 2 + q) * 64 + col] = (bf16)(p1 * sigmoidf_(p1) * p3);
          }
    }
  }
}

// ---------------- weight transpose + bf16 cast ----------------
template <int MODE>
__global__ __launch_bounds__(256) void transpose_bf16_kernel(
    const float* __restrict__ W, bf16* __restrict__ Wt, int R, int C, int Cpad, int half)
{
  __shared__ float tile[32][33];
  const int tc = blockIdx.x * 32;
  const int tr = blockIdx.y * 32;
  const int lx = threadIdx.x;
  const int ly = threadIdx.y;
  #pragma unroll
  for (int i = ly; i < 32; i += 8) {
    int r = tr + i, c = tc + lx;
    tile[i][lx] = (r < R && c < C) ? W[(size_t)r * C + c] : 0.f;
  }
  __syncthreads();
  #pragma unroll
  for (int i = ly; i < 32; i += 8) {
    int oc = tc + i;
    int orr = tr + lx;
    if (orr < R) {
      if (MODE == 0) {
        if (oc < Cpad) Wt[(size_t)oc * R + orr] = (bf16)tile[lx][i];
      } else {
        if (oc < C) {
          int orow = ((oc >> 6) << 7) + half + (oc & 63);
          Wt[(size_t)orow * R + orr] = (bf16)tile[lx][i];
        }
      }
    }
  }
}

// ---------------- rmsnorm (x fp32 -> out bf16) ----------------
__global__ __launch_bounds__(256) void rmsnorm_kernel(
    const float* __restrict__ x, const float* __restrict__ w, bf16* __restrict__ out)
{
  __shared__ float sbuf[4];
  const int row = blockIdx.x;
  const int tid = threadIdx.x;
  const float* xr = x + (size_t)row * DMOD;
  float v0 = xr[tid], v1 = xr[tid + 256], v2 = xr[tid + 512];
  float s = v0*v0 + v1*v1 + v2*v2;
  #pragma unroll
  for (int o = 32; o > 0; o >>= 1) s += __shfl_down(s, o, 64);
  if ((tid & 63) == 0) sbuf[tid >> 6] = s;
  __syncthreads();
  float tot = sbuf[0] + sbuf[1] + sbuf[2] + sbuf[3];
  float rms = rsqrtf(tot * (1.f / (float)DMOD) + EPS_);
  bf16* orow = out + (size_t)row * DMOD;
  orow[tid]       = (bf16)(v0 * rms * w[tid]);
  orow[tid + 256] = (bf16)(v1 * rms * w[tid + 256]);
  orow[tid + 512] = (bf16)(v2 * rms * w[tid + 512]);
}

// ---------------- 2-phase 128x128 GEMM (proven structure) ----------------
// EPI 1: momentum epilogue (vel = beta*vin + acc; x1 = x + vel).  EPI 2: Cf += acc.
template <int EPI>
__global__ __launch_bounds__(256) void gemm_w128(
    const bf16* __restrict__ A, const bf16* __restrict__ Bt, float* __restrict__ Cf,
    const float* __restrict__ xin, const float* __restrict__ vin,
    float* __restrict__ outv, const float* __restrict__ log_beta,
    int M, int N, int K, int nx)
{
  __shared__ alignas(16) unsigned short As[128 * 64];
  __shared__ alignas(16) unsigned short Bs[128 * 64];

  const int wg = swz_wg();
  const int m0 = (wg / nx) * 128, n0 = (wg % nx) * 128;
  const int tid  = threadIdx.x;
  const int wave = tid >> 6;
  const int lane = tid & 63;
  const int wr = wave >> 1, wc = wave & 1;

  f32x4 acc[4][4] = {};
  const int srow = lane >> 3;
  const int scol = ((lane & 7) ^ srow) * 8;
  const int lr = lane & 15;
  const int lsw = lr & 7;
  const int lk4 = lane >> 4;

  for (int k0 = 0; k0 < K; k0 += 64) {
    __syncthreads();
    #pragma unroll
    for (int it = 0; it < 4; ++it) {
      const int chunk = wave * 4 + it;
      const int row = chunk * 8 + srow;
      gload_lds16(A  + (size_t)(m0 + row) * K + k0 + scol, (char*)As + chunk * 1024);
      gload_lds16(Bt + (size_t)(n0 + row) * K + k0 + scol, (char*)Bs + chunk * 1024);
    }
    __syncthreads();
    #pragma unroll
    for (int kk = 0; kk < 2; ++kk) {
      bf16x8 af[4], bfr[4];
      #pragma unroll
      for (int i = 0; i < 4; ++i)
        af[i] = *reinterpret_cast<const bf16x8*>(
            &As[(wr*64 + i*16 + lr) * 64 + (((kk*4 + lk4) ^ lsw) * 8)]);
      #pragma unroll
      for (int i = 0; i < 4; ++i)
        bfr[i] = *reinterpret_cast<const bf16x8*>(
            &Bs[(wc*64 + i*16 + lr) * 64 + (((kk*4 + lk4) ^ lsw) * 8)]);
      #pragma unroll
      for (int mi = 0; mi < 4; ++mi)
        #pragma unroll
        for (int ni = 0; ni < 4; ++ni)
          acc[mi][ni] = __builtin_amdgcn_mfma_f32_16x16x32_bf16(af[mi], bfr[ni], acc[mi][ni], 0, 0, 0);
    }
  }

  const float beta = (EPI == 1) ? sigmoidf_(log_beta[0]) : 0.f;
  #pragma unroll
  for (int mi = 0; mi < 4; ++mi)
    #pragma unroll
    for (int ni = 0; ni < 4; ++ni)
      #pragma unroll
      for (int reg = 0; reg < 4; ++reg) {
        const int r = m0 + wr*64 + mi*16 + lk4 * 4 + reg;
        const int c = n0 + wc*64 + ni*16 + lr;
        const size_t off = (size_t)r * N + c;
        float v = acc[mi][ni][reg];
        if (EPI == 1) {
          float vel = beta * vin[off] + v;
          float x1  = xin[off] + vel;
          outv[off] = vel;
          Cf[off] = x1;
        } else {
          Cf[off] += v;
        }
      }
}

// ---------------- RG-LRU 2-pass chunked scan + fused conv ----------------
#define NCH  32
#define CLEN 64

__device__ __forceinline__ void lru_step(const bf16* row, int c, float coef,
                                         float& a, float& g)
{
  float v  = (float)row[2*DCONV + c];
  float r  = sigmoidf_((float)row[2*DCONV + DGRIF + c]);
  float is = sigmoidf_((float)row[2*DCONV + 2*DGRIF + c]);
  float la = coef * r;
  a = __expf(la);
  g = sqrtf(fmaxf(1.f - __expf(2.f * la), EPS_)) * (is * v);
}

__global__ __launch_bounds__(256) void lru_pass1(
    const bf16* __restrict__ g1, const float* __restrict__ lam,
    float* __restrict__ cA, float* __restrict__ cB)
{
  const int idx = blockIdx.x * 256 + threadIdx.x;
  const int c = idx % DGRIF;
  const int rest = idx / DGRIF;
  const int j = rest & (NCH - 1);
  const int b = rest / NCH;
  const float coef = -8.f * log1pf(__expf(lam[c]));
  const bf16* base = g1 + (size_t)(b * TSEQ + j * CLEN) * G1LD;
  float A = 1.f, Bv = 0.f;
  #pragma unroll 4
  for (int t = 0; t < CLEN; ++t) {
    float a, g;
    lru_step(base + (size_t)t * G1LD, c, coef, a, g);
    A *= a;
    Bv = a * Bv + g;
  }
  cA[((size_t)b * DGRIF + c) * NCH + j] = A;
  cB[((size_t)b * DGRIF + c) * NCH + j] = Bv;
}

__global__ __launch_bounds__(256) void lru_pass2(
    const bf16* __restrict__ g1, const float* __restrict__ lam,
    const float* __restrict__ cA, const float* __restrict__ cB,
    const float* __restrict__ dw, bf16* __restrict__ mixin)
{
  const int idx = blockIdx.x * 256 + threadIdx.x;
  const int c = idx % DGRIF;
  const int rest = idx / DGRIF;
  const int j = rest & (NCH - 1);
  const int b = rest / NCH;
  const float coef = -8.f * log1pf(__expf(lam[c]));
  float Hc = 0.f;
  const float* pa = cA + ((size_t)b * DGRIF + c) * NCH;
  const float* pb = cB + ((size_t)b * DGRIF + c) * NCH;
  for (int k = 0; k < j; ++k) Hc = pa[k] * Hc + pb[k];

  const int t0 = j * CLEN;
  const bf16* base = g1 + (size_t)(b * TSEQ + t0) * G1LD;
  const float w0 = dw[c*3], w1 = dw[c*3 + 1], w2 = dw[c*3 + 2];
  float u1 = (t0 >= 1) ? (float)base[-(ptrdiff_t)G1LD + c]     : 0.f;
  float u0 = (t0 >= 2) ? (float)base[-(ptrdiff_t)(2*G1LD) + c] : 0.f;

  bf16* mbase = mixin + (size_t)(b * TSEQ + t0) * DMOD;
  #pragma unroll 4
  for (int t = 0; t < CLEN; ++t) {
    const bf16* row = base + (size_t)t * G1LD;
    float u2 = (float)row[c];
    float gg = (float)row[DCONV + c];
    float conv = u0 * w0 + u1 * w1 + u2 * w2;
    mbase[(size_t)t * DMOD + c] = (bf16)(conv * (gg * sigmoidf_(gg)));
    u0 = u1; u1 = u2;
    float a, g;
    lru_step(row, c, coef, a, g);
    Hc = a * Hc + g;
    mbase[(size_t)t * DMOD + DCONV + c] = (bf16)Hc;
  }
}

// ---------------- launcher ----------------
extern "C" void kernel_launch(void* const* d_in, const int* in_sizes, int n_in,
                              void* d_out, int out_size, void* d_ws, size_t ws_size,
                              hipStream_t stream)
{
  const float* x         = (const float*)d_in[0];
  const float* vel_in    = (const float*)d_in[1];
  const float* pre_w     = (const float*)d_in[2];
  const float* conv_in_w = (const float*)d_in[3];
  const float* conv_dw   = (const float*)d_in[4];
  const float* gv        = (const float*)d_in[5];
  const float* gr        = (const float*)d_in[6];
  const float* gi        = (const float*)d_in[7];
  const float* lam       = (const float*)d_in[8];
  const float* out_w     = (const float*)d_in[9];
  const float* log_beta  = (const float*)d_in[10];
  const float* ffn_w     = (const float*)d_in[11];
  const float* w1        = (const float*)d_in[12];
  const float* w3        = (const float*)d_in[13];
  const float* w2        = (const float*)d_in[14];

  char* ws = (char*)d_ws;
  size_t off = 0;
  auto alloc = [&](size_t bytes) { void* p = ws + off; off += (bytes + 255) & ~(size_t)255; return p; };

  bf16*  WT_G1  = (bf16*)alloc((size_t)G1LD * DMOD * 2);
  bf16*  WT_OUT = (bf16*)alloc((size_t)DMOD * DMOD * 2);
  bf16*  WT_W13 = (bf16*)alloc((size_t)2 * DFFN * DMOD * 2);
  bf16*  WT_W2  = (bf16*)alloc((size_t)DMOD * DFFN * 2);
  float* CA     = (float*)alloc((size_t)BSZ * DGRIF * NCH * 4);
  float* CB     = (float*)alloc((size_t)BSZ * DGRIF * NCH * 4);
  bf16*  XN     = (bf16*)alloc((size_t)BT * DMOD * 2);
  bf16*  G1     = (bf16*)alloc((size_t)BT * G1LD * 2);
  bf16*  MIXIN  = (bf16*)alloc((size_t)BT * DMOD * 2);
  bf16*  H      = (bf16*)alloc((size_t)BT * DFFN * 2);
  bf16*  NORMED = (bf16*)alloc((size_t)BT * DMOD * 2);

  float* OUTX   = (float*)d_out;
  float* OUTV   = OUTX + (size_t)BT * DMOD;

  hipFuncSetAttribute((const void*)gemm256<0>, hipFuncAttributeMaxDynamicSharedMemorySize, 131072);
  hipFuncSetAttribute((const void*)gemm256<1>, hipFuncAttributeMaxDynamicSharedMemorySize, 131072);

  const dim3 tb(32, 8);
  hipMemsetAsync(WT_G1 + (size_t)NG1 * DMOD, 0, (size_t)(G1LD - NG1) * DMOD * 2, stream);
  transpose_bf16_kernel<0><<<dim3(DMOD/32,  DMOD/32), tb, 0, stream>>>(conv_in_w, WT_G1, DMOD, DMOD, DMOD, 0);
  transpose_bf16_kernel<0><<<dim3(DGRIF/32, DMOD/32), tb, 0, stream>>>(gv, WT_G1 + (size_t)(2*DCONV) * DMOD, DMOD, DGRIF, DGRIF, 0);
  transpose_bf16_kernel<0><<<dim3(DGRIF/32, DMOD/32), tb, 0, stream>>>(gr, WT_G1 + (size_t)(2*DCONV + DGRIF) * DMOD, DMOD, DGRIF, DGRIF, 0);
  transpose_bf16_kernel<0><<<dim3(DGRIF/32, DMOD/32), tb, 0, stream>>>(gi, WT_G1 + (size_t)(2*DCONV + 2*DGRIF) * DMOD, DMOD, DGRIF, DGRIF, 0);
  transpose_bf16_kernel<0><<<dim3(DMOD/32,  DMOD/32), tb, 0, stream>>>(out_w, WT_OUT, DMOD, DMOD, DMOD, 0);
  transpose_bf16_kernel<1><<<dim3(DFFN/32,  DMOD/32), tb, 0, stream>>>(w1, WT_W13, DMOD, DFFN, DFFN, 0);
  transpose_bf16_kernel<1><<<dim3(DFFN/32,  DMOD/32), tb, 0, stream>>>(w3, WT_W13, DMOD, DFFN, DFFN, 64);
  transpose_bf16_kernel<0><<<dim3(DMOD/32,  DFFN/32), tb, 0, stream>>>(w2, WT_W2, DFFN, DMOD, DMOD, 0);

  // pre-norm
  rmsnorm_kernel<<<BT, 256, 0, stream>>>(x, pre_w, XN);

  // GEMM1 (8-phase v2): [8192,768] @ [768,2048pad] -> G1 (bf16, stride 2048)
  gemm256<0><<<(BT/256) * (G1LD/256), 512, 131072, stream>>>(XN, WT_G1, G1, DMOD, G1LD/256, G1LD);

  // RG-LRU + fused conv -> MIXIN
  lru_pass1<<<(BSZ * NCH * DGRIF) / 256, 256, 0, stream>>>(G1, lam, CA, CB);
  lru_pass2<<<(BSZ * NCH * DGRIF) / 256, 256, 0, stream>>>(G1, lam, CA, CB, conv_dw, MIXIN);

  // GEMM2 (128^2, momentum epilogue): OUTX = x + vel, OUTV = vel
  gemm_w128<1><<<(DMOD/128) * (BT/128), 256, 0, stream>>>(MIXIN, WT_OUT, OUTX, x, vel_in, OUTV,
                                                          log_beta, BT, DMOD, DMOD, DMOD/128);

  // ffn rmsnorm on x1
  rmsnorm_kernel<<<BT, 256, 0, stream>>>(OUTX, ffn_w, NORMED);

  // fused FFN up-proj + SwiGLU (8-phase v2) -> H
  gemm256<1><<<(BT/256) * (2*DFFN/256), 512, 131072, stream>>>(NORMED, WT_W13, H, DMOD, 2*DFFN/256, DFFN);

  // down-proj (128^2, accumulate): OUTX += H @ w2
  gemm_w128<2><<<(DMOD/128) * (BT/128), 256, 0, stream>>>(H, WT_W2, OUTX, nullptr, nullptr, nullptr,
                                                          nullptr, BT, DMOD, DFFN, DMOD/128);
}